// Round 4
// baseline (271.832 us; speedup 1.0000x reference)
//
#include <hip/hip_runtime.h>

#define BB 32
#define TT 512
#define DD 768
#define NLANES 192              // = DD/4 float4 lanes per row

typedef float f4 __attribute__((ext_vector_type(4)));

// Max-TLP two-kernel form. Rounds 0-3 proved load-balance and store flavor
// are not the limiter (three structural variants all ~122 us kernel-side,
// 2.1 TB/s effective vs 6.3 TB/s m13 copy ceiling). The shared residue was
// the per-block serial run-walk whose dynamic store counts force vmcnt(0)
// drains at every run boundary. This version deletes all serial structure:
//
// Kernel A (32 blocks): per-batch scan + full inverse map idx[b][r]
//   (= searchsorted(cum, r, 'right'), or -1 for masked tail rows).
// Kernel B (t_out x 32 blocks, one block per output row): broadcast idx
//   load -> one coalesced 3072 B x-row load -> one coalesced 3072 B store.
//   Pure streaming, 205K waves, nothing dynamic per wave.

__global__ __launch_bounds__(TT) void lr_scan_kernel(
    const float* __restrict__ dur, int* __restrict__ idx, int t_out) {
    __shared__ int scum[TT];
    const int b = blockIdx.x;
    const int tid = threadIdx.x;

    float d = fmaxf(dur[b * TT + tid], 0.0f);
    scum[tid] = (int)floorf(d + 0.5f);
    __syncthreads();

    // Hillis-Steele inclusive scan, 512 threads / 512 elements.
    #pragma unroll
    for (int off = 1; off < TT; off <<= 1) {
        int v = (tid >= off) ? scum[tid - off] : 0;
        __syncthreads();
        scum[tid] += v;
        __syncthreads();
    }

    const int total = scum[TT - 1];
    // Inverse map: idx[r] = upper_bound(cum, r) for r < total, else -1.
    for (int p = tid; p < t_out; p += TT) {
        int v = -1;
        if (p < total) {
            int lo = 0, hi = TT;
            while (lo < hi) {
                int mid = (lo + hi) >> 1;
                if (scum[mid] <= p) lo = mid + 1; else hi = mid;
            }
            v = lo;                      // p < total guarantees lo <= TT-1
        }
        idx[b * t_out + p] = v;
    }
}

__global__ __launch_bounds__(NLANES) void lr_scatter_kernel(
    const float* __restrict__ x, const int* __restrict__ idx,
    float* __restrict__ out, int t_out) {
    const int b = blockIdx.y;
    const int r = blockIdx.x;
    const int tid = threadIdx.x;

    const int t = idx[b * t_out + r];    // same addr across block: broadcast
    f4 v = (f4)(0.0f);
    if (t >= 0)                          // block-uniform branch
        v = ((const f4*)(x + (size_t)b * TT * DD))[(size_t)t * NLANES + tid];
    ((f4*)(out + (size_t)b * (size_t)t_out * DD))[(size_t)r * NLANES + tid] = v;
}

extern "C" void kernel_launch(void* const* d_in, const int* in_sizes, int n_in,
                              void* d_out, int out_size, void* d_ws, size_t ws_size,
                              hipStream_t stream) {
    const float* x   = (const float*)d_in[0];
    const float* dur = (const float*)d_in[1];
    float* out = (float*)d_out;
    (void)in_sizes; (void)n_in; (void)ws_size;

    const int t_out = out_size / (BB * DD);
    int* idx = (int*)d_ws;               // BB * t_out * 4 B  (~273 KB)

    lr_scan_kernel<<<BB, TT, 0, stream>>>(dur, idx, t_out);
    lr_scatter_kernel<<<dim3(t_out, BB), NLANES, 0, stream>>>(x, idx, out, t_out);
}

// Round 5
// 255.077 us; speedup vs baseline: 1.0657x; 1.0657x over previous
//
#include <hip/hip_runtime.h>

#define BB 32
#define TT 512
#define DD 768
#define NTHREADS 192            // = DD/4 float4 lanes per row
#define TOK_PER_BLOCK 8         // source tokens per block
#define BLOCKS_PER_BATCH (TT / TOK_PER_BLOCK)   // 64

typedef float f4 __attribute__((ext_vector_type(4)));

// ROUND 5 = MEASUREMENT ROUND. Rounds 0-4: four structurally different
// kernels (token-centric NT, row-balanced NT, row-balanced plain, max-TLP
// two-kernel memcpy-shaped) all land 252.7-271.8 us. Structural causes are
// exhausted; the open question is whether kernel time is ~120 us (store path
// capped ~2 TB/s) or ~45-60 us (near roofline, floor is harness reset).
// This submission keeps the BEST kernel (round-0, 252.7 us) VERBATIM and
// prepends a pure store-only zero pass over the full output buffer.
// DeltaDur vs 252.7 = duration of that pass = direct measurement of
// achievable store BW on this buffer: +33 us -> 6.3 TB/s (we're at
// roofline); +100 us -> 2.1 TB/s (store path is the target).

__global__ __launch_bounds__(256) void lr_zero_kernel(f4* __restrict__ out,
                                                      long n4) {
    const long stride = (long)gridDim.x * 256;
    const f4 z = (f4)(0.0f);
    for (long i = (long)blockIdx.x * 256 + threadIdx.x; i < n4; i += stride)
        out[i] = z;
}

// ---- round-0 kernel, verbatim ----
__global__ __launch_bounds__(NTHREADS) void lr_fused_kernel(
    const float* __restrict__ x, const float* __restrict__ dur,
    float* __restrict__ out, int t_out) {
    __shared__ int scum[TT];
    const int b = blockIdx.y;
    const int tid = threadIdx.x;

    // reps into LDS
    for (int i = tid; i < TT; i += NTHREADS) {
        float d = fmaxf(dur[b * TT + i], 0.0f);
        scum[i] = (int)floorf(d + 0.5f);
    }
    __syncthreads();

    // Hillis-Steele inclusive scan over 512 elements with 192 threads.
    #pragma unroll
    for (int off = 1; off < TT; off <<= 1) {
        const int i0 = tid, i1 = tid + NTHREADS, i2 = tid + 2 * NTHREADS;
        int v0 = (i0 >= off) ? scum[i0 - off] : 0;
        int v1 = (i1 >= off) ? scum[i1 - off] : 0;
        int v2 = (i2 < TT && i2 >= off) ? scum[i2 - off] : 0;
        __syncthreads();
        scum[i0] += v0;
        scum[i1] += v1;
        if (i2 < TT) scum[i2] += v2;
        __syncthreads();
    }

    // Scatter this block's 8 source tokens.
    const int s0 = blockIdx.x * TOK_PER_BLOCK;
    const f4* xb = (const f4*)(x + (size_t)b * TT * DD);
    f4* ob = (f4*)(out + (size_t)b * (size_t)t_out * DD);

    #pragma unroll
    for (int k = 0; k < TOK_PER_BLOCK; ++k) {
        const int t = s0 + k;
        const int start = (t == 0) ? 0 : scum[t - 1];
        const int end = scum[t];
        if (end > start) {                     // block-uniform branch
            const f4 v = xb[(size_t)t * NTHREADS + tid];
            for (int p = start; p < end; ++p)  // 0..8 iters, block-uniform
                __builtin_nontemporal_store(v, &ob[(size_t)p * NTHREADS + tid]);
        }
    }

    // Tail zero: rows [total, t_out) striped across the batch's 64 blocks.
    const int total = scum[TT - 1];
    const f4 z = (f4)(0.0f);
    for (int pos = total + blockIdx.x; pos < t_out; pos += BLOCKS_PER_BATCH)
        __builtin_nontemporal_store(z, &ob[(size_t)pos * NTHREADS + tid]);
}

extern "C" void kernel_launch(void* const* d_in, const int* in_sizes, int n_in,
                              void* d_out, int out_size, void* d_ws, size_t ws_size,
                              hipStream_t stream) {
    const float* x   = (const float*)d_in[0];
    const float* dur = (const float*)d_in[1];
    float* out = (float*)d_out;
    (void)d_ws; (void)ws_size; (void)in_sizes; (void)n_in;

    const int t_out = out_size / (BB * DD);

    // Measurement pass: pure stores over the full output buffer.
    const long n4 = (long)out_size / 16;
    lr_zero_kernel<<<2048, 256, 0, stream>>>((f4*)out, n4);

    dim3 grid(BLOCKS_PER_BATCH, BB);           // 64 x 32 blocks
    lr_fused_kernel<<<grid, NTHREADS, 0, stream>>>(x, dur, out, t_out);
}